// Round 4
// baseline (3174.013 us; speedup 1.0000x reference)
//
#include <hip/hip_runtime.h>
#include <hip/hip_bf16.h>

typedef __bf16 bf16;
typedef bf16 bf16x8 __attribute__((ext_vector_type(8)));
typedef bf16 bf16x4 __attribute__((ext_vector_type(4)));
typedef float f32x4 __attribute__((ext_vector_type(4)));

#define HID 1024
#define FFD 2048
#define GRID_CAP 512

typedef __attribute__((address_space(3))) void lds_void;
typedef const __attribute__((address_space(1))) void gm_void;

__device__ __forceinline__ void gload_lds16(const bf16* g, bf16* l)
{
    __builtin_amdgcn_global_load_lds((gm_void*)g, (lds_void*)l, 16, 0, 0);
}

struct CvtEnt { const float* src; bf16* dst; int b0; };
struct CvtArgs { CvtEnt e[14]; int n; };
struct CvtTEnt { const float* src; bf16* dst; int R, C, b0; };
struct CvtTArgs { CvtTEnt e[4]; int n; };

union LdsU {
    struct { bf16 As[128][32], Bs[128][32]; } g;
    struct { float q[16][256], k[16][256], v[16][256], sc[16][16]; } a;
    struct { bf16 t[32][33]; } t;
    float red[8];
};

struct MP {
    const float* nf; const int* ei; const int* tgt;
    const float *g1bl, *g1br, *g1att, *g1bias, *g2att, *g2bias;
    const float *xa_in_b, *xa_out_b;
    const float *xl_l1_b, *xl_l2_b, *xl_n1_g, *xl_n1_b, *xl_n2_g, *xl_n2_b;
    const float *enc_in_b, *enc_out_b, *enc_l1_b, *enc_l2_b;
    const float *enc_n1_g, *enc_n1_b, *enc_n2_g, *enc_n2_b;
    const float *cls_w, *cls_b;
    bf16 *w1lT, *w1rT, *w2T; float* bias2;
    bf16 *xa_v_b, *xa_o_b, *xl1w, *xl2w;
    bf16 *einw[2], *eoutw[2], *el1w[2], *el2w[2];
    bf16* imgb;
    int *f1, *f2, *cntE0, *cntE1, *cnt1, *cnt2, *bar;
    int *map1, *map2, *list1, *list2, *srcs0, *srcs1;
    bf16 *nf2c, *nf1c, *xlc, *xrc, *x1c, *x12c;
    float* x2c; bf16* vprojb; float* attnb;
    float* srcbuf; bf16 *srcb16, *h1b, *ffb16;
    float* skpart; float* outp;
    int DF, Nn, E, L, B, R, cap1;
};

// ---------------------------------------------------------------------------
// device-wide barrier: agent-scope atomics + fences (cross-XCD safe).
// Correct ONLY when all blocks are co-resident (cooperative launch).
// ---------------------------------------------------------------------------
__device__ __forceinline__ void gsync(int* bar, int target)
{
    __syncthreads();
    __threadfence();
    if (threadIdx.x == 0) {
        __hip_atomic_fetch_add(bar, 1, __ATOMIC_RELEASE, __HIP_MEMORY_SCOPE_AGENT);
        while (__hip_atomic_load(bar, __ATOMIC_ACQUIRE, __HIP_MEMORY_SCOPE_AGENT) < target)
            __builtin_amdgcn_s_sleep(2);
    }
    __syncthreads();
    __threadfence();
}

// ---------------------------------------------------------------------------
// stage device functions (verbatim ports of the round-2 kernels)
// ---------------------------------------------------------------------------
__device__ void dev_cvt_t(const CvtTArgs& a, int job, LdsU& u)
{
    int k = 0;
    while (k + 1 < a.n && job >= a.e[k + 1].b0) ++k;
    const CvtTEnt en = a.e[k];
    const int lb = job - en.b0;
    const int CB = en.C >> 5;
    const int c0 = (lb % CB) * 32, r0 = (lb / CB) * 32;
    const int tx = threadIdx.x & 31, ty = threadIdx.x >> 5;
#pragma unroll
    for (int i = ty; i < 32; i += 8)
        u.t.t[i][tx] = (bf16)en.src[(long)(r0 + i) * en.C + c0 + tx];
    __syncthreads();
#pragma unroll
    for (int i = ty; i < 32; i += 8)
        en.dst[(long)(c0 + i) * en.R + r0 + tx] = u.t.t[tx][i];
    __syncthreads();
}

__device__ void dev_cvt(const CvtArgs& a, int job)
{
    int k = 0;
    while (k + 1 < a.n && job >= a.e[k + 1].b0) ++k;
    const long i = ((long)(job - a.e[k].b0) * 256 + threadIdx.x) * 4;
    float4 f = *(const float4*)&a.e[k].src[i];
    bf16x4 v = {(bf16)f.x, (bf16)f.y, (bf16)f.z, (bf16)f.w};
    *(bf16x4*)&a.e[k].dst[i] = v;
}

__device__ void dev_pass0(const MP& p, int j)
{
    if (j == 0 && (int)threadIdx.x < p.L) p.f1[p.tgt[threadIdx.x]] = 1;
    int e = j * 256 + threadIdx.x;
    if (e >= p.E) return;
    int d = p.ei[e];
    int c = -1;
    for (int l = 0; l < p.L; ++l) if (p.tgt[l] == d) { c = l; break; }
    if (c < 0) return;
    int s = atomicAdd(&p.cntE0[c], 1);
    if (s < 128) { int sr = p.ei[p.E + e]; p.srcs0[c * 128 + s] = sr; p.f1[sr] = 1; }
}

__device__ void dev_pass1(const MP& p, int j)
{
    int e = j * 256 + threadIdx.x;
    if (e >= p.E) return;
    int d = p.ei[e];
    if (!p.f1[d]) return;
    int c = p.map1[d];
    int s = atomicAdd(&p.cntE1[c], 1);
    if (s < 128) { int sr = p.ei[p.E + e]; p.srcs1[c * 128 + s] = sr; p.f2[sr] = 1; }
}

__device__ void dev_compact(const int* flags, int* map, int* list, int* cnt, int n, int j)
{
    int i = j * 256 + threadIdx.x;
    if (i < n && flags[i]) {
        int ppos = atomicAdd(cnt, 1);
        list[ppos] = i;
        map[i] = ppos;
    }
}

__device__ void dev_gather(const float* nf, bf16* dst, const int* list, int cnt,
                           int r0, int stride, int DF)
{
    for (int r = r0; r < cnt; r += stride) {
        const long i = (long)list[r] * DF;
        const long o = (long)r * DF;
        for (int c = threadIdx.x * 4; c < DF; c += 1024) {
            float4 f = *(const float4*)&nf[i + c];
            bf16x4 v = {(bf16)f.x, (bf16)f.y, (bf16)f.z, (bf16)f.w};
            *(bf16x4*)&dst[o + c] = v;
        }
    }
}

__device__ void dev_gemm(const bf16* __restrict__ A, const bf16* __restrict__ Bt,
                         const float* __restrict__ bias, void* __restrict__ Cp,
                         int M, int N, int K, const int* cnt, int act, int outbf,
                         int bn, int bm, LdsU& u)
{
    int Meff = cnt ? *cnt : M;
    if (Meff <= 0 || bm * 128 >= Meff) return;

    const int tid  = threadIdx.x;
    const int lane = tid & 63, wave = tid >> 6;
    const int wr   = wave >> 1, wc = wave & 1;

    f32x4 acc[4][4] = {};

    const int srow = wave * 16 + (lane >> 2);
    const int scol = (lane & 3) << 3;
    const long ga0 = (long)min(bm * 128 + srow,      Meff - 1) * K + scol;
    const long ga1 = (long)min(bm * 128 + srow + 64, Meff - 1) * K + scol;
    const long gb0 = (long)(bn * 128 + srow)      * K + scol;
    const long gb1 = (long)(bn * 128 + srow + 64) * K + scol;
    bf16* ldsA0 = &u.g.As[0][0] + wave * 512;
    bf16* ldsA1 = &u.g.As[0][0] + 2048 + wave * 512;
    bf16* ldsB0 = &u.g.Bs[0][0] + wave * 512;
    bf16* ldsB1 = &u.g.Bs[0][0] + 2048 + wave * 512;

    const int quad = lane >> 4;
    const int mr   = lane & 15;
    const int kf   = quad * 8;

    for (int k0 = 0; k0 < K; k0 += 32) {
        gload_lds16(A + ga0 + k0, ldsA0);
        gload_lds16(A + ga1 + k0, ldsA1);
        gload_lds16(Bt + gb0 + k0, ldsB0);
        gload_lds16(Bt + gb1 + k0, ldsB1);
        __syncthreads();

        bf16x8 af[4], bfr[4];
#pragma unroll
        for (int i = 0; i < 4; ++i) af[i]  = *(const bf16x8*)&u.g.As[wr * 64 + i * 16 + mr][kf];
#pragma unroll
        for (int j = 0; j < 4; ++j) bfr[j] = *(const bf16x8*)&u.g.Bs[wc * 64 + j * 16 + mr][kf];
#pragma unroll
        for (int i = 0; i < 4; ++i)
#pragma unroll
            for (int j = 0; j < 4; ++j)
                acc[i][j] = __builtin_amdgcn_mfma_f32_16x16x32_bf16(af[i], bfr[j], acc[i][j], 0, 0, 0);
        __syncthreads();
    }

    const int crow = quad * 4;
#pragma unroll
    for (int i = 0; i < 4; ++i) {
#pragma unroll
        for (int j = 0; j < 4; ++j) {
            const int   col = bn * 128 + wc * 64 + j * 16 + mr;
            const float bv  = bias[col];
#pragma unroll
            for (int r = 0; r < 4; ++r) {
                const int row = bm * 128 + wr * 64 + i * 16 + crow + r;
                if (row < Meff) {
                    float v = acc[i][j][r] + bv;
                    if (act) v = fmaxf(v, 0.f);
                    if (outbf) ((bf16*)Cp)[(long)row * N + col] = (bf16)v;
                    else       ((float*)Cp)[(long)row * N + col] = v;
                }
            }
        }
    }
}

__device__ void dev_bsk(const bf16* __restrict__ A, const bf16* __restrict__ Bt,
                        float* __restrict__ part, int M, int N, int K, int KS,
                        int bn, int bm, int kz, LdsU& u)
{
    const int tid  = threadIdx.x;
    const int lane = tid & 63, wave = tid >> 6;
    const int wr   = wave >> 1, wc = wave & 1;

    f32x4 acc[4][4] = {};

    const int srow = wave * 16 + (lane >> 2);
    const int scol = (lane & 3) << 3;
    const long ga0 = (long)min(bm * 128 + srow,      M - 1) * K + scol;
    const long ga1 = (long)min(bm * 128 + srow + 64, M - 1) * K + scol;
    const long gb0 = (long)(bn * 128 + srow)      * K + scol;
    const long gb1 = (long)(bn * 128 + srow + 64) * K + scol;
    bf16* ldsA0 = &u.g.As[0][0] + wave * 512;
    bf16* ldsA1 = &u.g.As[0][0] + 2048 + wave * 512;
    bf16* ldsB0 = &u.g.Bs[0][0] + wave * 512;
    bf16* ldsB1 = &u.g.Bs[0][0] + 2048 + wave * 512;

    const int quad = lane >> 4;
    const int mr   = lane & 15;
    const int kf   = quad * 8;

    const int Kc = K / KS, kbeg = kz * Kc, kend = kbeg + Kc;
    for (int k0 = kbeg; k0 < kend; k0 += 32) {
        gload_lds16(A + ga0 + k0, ldsA0);
        gload_lds16(A + ga1 + k0, ldsA1);
        gload_lds16(Bt + gb0 + k0, ldsB0);
        gload_lds16(Bt + gb1 + k0, ldsB1);
        __syncthreads();

        bf16x8 af[4], bfr[4];
#pragma unroll
        for (int i = 0; i < 4; ++i) af[i]  = *(const bf16x8*)&u.g.As[wr * 64 + i * 16 + mr][kf];
#pragma unroll
        for (int j = 0; j < 4; ++j) bfr[j] = *(const bf16x8*)&u.g.Bs[wc * 64 + j * 16 + mr][kf];
#pragma unroll
        for (int i = 0; i < 4; ++i)
#pragma unroll
            for (int j = 0; j < 4; ++j)
                acc[i][j] = __builtin_amdgcn_mfma_f32_16x16x32_bf16(af[i], bfr[j], acc[i][j], 0, 0, 0);
        __syncthreads();
    }

    float* dst = part + (size_t)kz * M * N;
    const int crow = quad * 4;
#pragma unroll
    for (int i = 0; i < 4; ++i) {
#pragma unroll
        for (int j = 0; j < 4; ++j) {
            const int col = bn * 128 + wc * 64 + j * 16 + mr;
#pragma unroll
            for (int r = 0; r < 4; ++r) {
                const int row = bm * 128 + wr * 64 + i * 16 + crow + r;
                if (row < M) dst[(long)row * N + col] = acc[i][j][r];
            }
        }
    }
}

__device__ void dev_red16(const float* part, const float* bias, bf16* C,
                          long MN, int N, int KS, int job)
{
    long i = (long)job * 1024 + threadIdx.x * 4;
    if (i >= MN) return;
    float4 s = *(const float4*)&part[i];
    for (int k = 1; k < KS; ++k) {
        float4 q = *(const float4*)&part[(size_t)k * MN + i];
        s.x += q.x; s.y += q.y; s.z += q.z; s.w += q.w;
    }
    const int col = (int)(i % N);
    float4 bv = *(const float4*)&bias[col];
    s.x = fmaxf(s.x + bv.x, 0.f); s.y = fmaxf(s.y + bv.y, 0.f);
    s.z = fmaxf(s.z + bv.z, 0.f); s.w = fmaxf(s.w + bv.w, 0.f);
    bf16x4 v = {(bf16)s.x, (bf16)s.y, (bf16)s.z, (bf16)s.w};
    *(bf16x4*)&C[i] = v;
}

__device__ void dev_ln_finish(float v[4], int c0, const float* g, const float* beta,
                              float* outrow, bf16* outb, float* red)
{
    float s1 = v[0] + v[1] + v[2] + v[3];
    float s2 = v[0] * v[0] + v[1] * v[1] + v[2] * v[2] + v[3] * v[3];
    for (int o = 32; o; o >>= 1) { s1 += __shfl_down(s1, o); s2 += __shfl_down(s2, o); }
    const int wave = threadIdx.x >> 6, lane = threadIdx.x & 63;
    if (lane == 0) { red[wave] = s1; red[4 + wave] = s2; }
    __syncthreads();
    if (threadIdx.x == 0) {
        red[0] += red[1] + red[2] + red[3];
        red[4] += red[5] + red[6] + red[7];
    }
    __syncthreads();
    const float mean = red[0] * (1.f / HID);
    const float var  = fmaxf(red[4] * (1.f / HID) - mean * mean, 0.f);
    const float rstd = rsqrtf(var + 1e-5f);
#pragma unroll
    for (int k = 0; k < 4; ++k) {
        int c = c0 + k;
        float o = (v[k] - mean) * rstd * g[c] + beta[c];
        outrow[c] = o;
        outb[c] = (bf16)o;
    }
    __syncthreads();
}

__device__ void dev_red_ln(const float* part, const float* bias, float* srcio,
                           bf16* srcb, const float* g, const float* beta,
                           long MN, int KS, int row, float* red)
{
    const int c0 = threadIdx.x * 4;
    const long base = (long)row * HID + c0;
    float4 s = *(const float4*)&part[base];
    for (int k = 1; k < KS; ++k) {
        float4 q = *(const float4*)&part[(size_t)k * MN + base];
        s.x += q.x; s.y += q.y; s.z += q.z; s.w += q.w;
    }
    float4 bv = *(const float4*)&bias[c0];
    float4 rv = *(const float4*)&srcio[base];
    float v[4] = {s.x + bv.x + rv.x, s.y + bv.y + rv.y,
                  s.z + bv.z + rv.z, s.w + bv.w + rv.w};
    dev_ln_finish(v, c0, g, beta, srcio + (long)row * HID, srcb + (long)row * HID, red);
}

__device__ void dev_ln_cross(const MP& p, int row, float* red)
{
    const int b = row / p.L, l = row - b * p.L;
    const int c0 = threadIdx.x * 4;
    float v[4];
#pragma unroll
    for (int k = 0; k < 4; ++k)
        v[k] = p.x2c[(long)l * HID + c0 + k] + p.attnb[(long)b * HID + c0 + k];
    dev_ln_finish(v, c0, p.xl_n1_g, p.xl_n1_b,
                  p.srcbuf + (long)row * HID, p.srcb16 + (long)row * HID, red);
}

__device__ void dev_wave1(const MP& p, int job, int c1)
{
    const int wave = threadIdx.x >> 6, lane = threadIdx.x & 63;
    const int w = job * 4 + wave;
    if (w >= c1) return;
    int deg = min(p.cntE1[w], 128);
    const int base = w * 128;
    int my_src = p.map2[p.srcs1[base + min(lane, deg - 1)]];
    int my_src2 = 0;
    if (deg > 64) my_src2 = p.map2[p.srcs1[base + 64 + min(lane, deg - 65)]];

    const int c0 = lane * 16;
    float xrf[16], av[16];
    {
        bf16x8 r0 = *(const bf16x8*)&p.xrc[(long)w * HID + c0];
        bf16x8 r1 = *(const bf16x8*)&p.xrc[(long)w * HID + c0 + 8];
#pragma unroll
        for (int t = 0; t < 8; ++t) { xrf[t] = (float)r0[t]; xrf[8 + t] = (float)r1[t]; }
        float4 t0 = *(const float4*)&p.g1att[c0],     t1 = *(const float4*)&p.g1att[c0 + 4];
        float4 t2 = *(const float4*)&p.g1att[c0 + 8], t3 = *(const float4*)&p.g1att[c0 + 12];
        av[0]=t0.x; av[1]=t0.y; av[2]=t0.z;  av[3]=t0.w;
        av[4]=t1.x; av[5]=t1.y; av[6]=t1.z;  av[7]=t1.w;
        av[8]=t2.x; av[9]=t2.y; av[10]=t2.z; av[11]=t2.w;
        av[12]=t3.x; av[13]=t3.y; av[14]=t3.z; av[15]=t3.w;
    }

    float m = -1e30f, s = 0.f;
    float acc[16];
#pragma unroll
    for (int t = 0; t < 16; ++t) acc[t] = 0.f;

    int sj = __shfl(my_src, 0);
    bf16x8 na0 = *(const bf16x8*)&p.xlc[(long)sj * HID + c0];
    bf16x8 na1 = *(const bf16x8*)&p.xlc[(long)sj * HID + c0 + 8];

    for (int j = 0; j < deg; ++j) {
        bf16x8 x0 = na0, x1 = na1;
        if (j + 1 < deg) {
            int msrc = (j + 1 < 64) ? my_src : my_src2;
            int sn = __shfl(msrc, (j + 1) & 63);
            na0 = *(const bf16x8*)&p.xlc[(long)sn * HID + c0];
            na1 = *(const bf16x8*)&p.xlc[(long)sn * HID + c0 + 8];
        }
        float xf[16];
#pragma unroll
        for (int t = 0; t < 8; ++t) { xf[t] = (float)x0[t]; xf[8 + t] = (float)x1[t]; }
        float partial = 0.f;
#pragma unroll
        for (int t = 0; t < 16; ++t) {
            float v = xf[t] + xrf[t];
            v = v > 0.f ? v : 0.2f * v;
            partial += v * av[t];
        }
#pragma unroll
        for (int o = 1; o < 16; o <<= 1) partial += __shfl_xor(partial, o);
        float mn = fmaxf(m, partial);
        float f = __expf(m - mn);
        float pp = __expf(partial - mn);
        s = s * f + pp;
#pragma unroll
        for (int t = 0; t < 16; ++t) acc[t] = acc[t] * f + pp * xf[t];
        m = mn;
    }

    const float dinv = 1.f / (s + 1e-16f);
    float bv[16];
    {
        float4 t0 = *(const float4*)&p.g1bias[c0],     t1 = *(const float4*)&p.g1bias[c0 + 4];
        float4 t2 = *(const float4*)&p.g1bias[c0 + 8], t3 = *(const float4*)&p.g1bias[c0 + 12];
        bv[0]=t0.x; bv[1]=t0.y; bv[2]=t0.z;  bv[3]=t0.w;
        bv[4]=t1.x; bv[5]=t1.y; bv[6]=t1.z;  bv[7]=t1.w;
        bv[8]=t2.x; bv[9]=t2.y; bv[10]=t2.z; bv[11]=t2.w;
        bv[12]=t3.x; bv[13]=t3.y; bv[14]=t3.z; bv[15]=t3.w;
    }
    bf16x8 w0, w1;
#pragma unroll
    for (int t = 0; t < 16; ++t) {
        float v = acc[t] * dinv + bv[t];
        v = v > 0.f ? v : 0.2f * v;
        if (t < 8) w0[t] = (bf16)v; else w1[t - 8] = (bf16)v;
    }
    *(bf16x8*)&p.x1c[(long)w * HID + c0] = w0;
    *(bf16x8*)&p.x1c[(long)w * HID + c0 + 8] = w1;
}

__device__ void dev_wave2(const MP& p, int job)
{
    const int wave = threadIdx.x >> 6, lane = threadIdx.x & 63;
    const int w = job * 4 + wave;
    if (w >= p.L) return;
    const int n = p.tgt[w];
    int c = 0;
    for (int l = 0; l < p.L; ++l) if (p.tgt[l] == n) { c = l; break; }
    int deg = min(p.cntE0[c], 128);
    const int base = c * 128;
    int my_src = p.map1[p.srcs0[base + min(lane, deg - 1)]];
    int my_src2 = 0;
    if (deg > 64) my_src2 = p.map1[p.srcs0[base + 64 + min(lane, deg - 65)]];

    const int c0 = lane * 16;
    const long LD = 2 * HID;
    float xrf[16], av[16];
    {
        const long xrr = (long)p.map1[n] * LD + HID + c0;
        bf16x8 r0 = *(const bf16x8*)&p.x12c[xrr];
        bf16x8 r1 = *(const bf16x8*)&p.x12c[xrr + 8];
#pragma unroll
        for (int t = 0; t < 8; ++t) { xrf[t] = (float)r0[t]; xrf[8 + t] = (float)r1[t]; }
        float4 t0 = *(const float4*)&p.g2att[c0],     t1 = *(const float4*)&p.g2att[c0 + 4];
        float4 t2 = *(const float4*)&p.g2att[c0 + 8], t3 = *(const float4*)&p.g2att[c0 + 12];
        av[0]=t0.x; av[1]=t0.y; av[2]=t0.z;  av[3]=t0.w;
        av[4]=t1.x; av[5]=t1.y; av[6]=t1.z;  av[7]=t1.w;
        av[8]=t2.x; av[9]=t2.y; av[10]=t2.z; av[11]=t2.w;
        av[12]=t3.x; av[13]=t3.y; av[14]=t3.z; av[15]=t3.w;
    }

    float m = -1e30f, s = 0.f;
    float acc[16];
#pragma unroll
    for (int t = 0; t < 16; ++t) acc[t] = 0.f;

    int sj = __shfl(my_src, 0);
    bf16x8 na0 = *(const bf16x8*)&p.x12c[(long)sj * LD + c0];
    bf16x8 na1 = *(const bf16x8*)&p.x12c[(long)sj * LD + c0 + 8];

    for (int j = 0; j < deg; ++j) {
        bf16x8 x0 = na0, x1 = na1;
        if (j + 1 < deg) {
            int msrc = (j + 1 < 64) ? my_src : my_src2;
            int sn = __shfl(msrc, (j + 1) & 63);
            na0 = *(const bf16x8*)&p.x12c[(long)sn * LD + c0];
            na1 = *(const bf16x8*)&p.x12c[(long)sn * LD + c0 + 8];
        }
        float xf[16];
#pragma unroll
        for (int t = 0; t < 8; ++t) { xf[t] = (float)x0[t]; xf[8 + t] = (float)x1[t]; }
        float partial = 0.f;
#pragma unroll
        for (int t = 0; t < 16; ++t) {
            float v = xf[t] + xrf[t];
            v = v > 0.f ? v : 0.2f * v;
            partial += v * av[t];
        }
#pragma unroll
        for (int o = 1; o < 64; o <<= 1) partial += __shfl_xor(partial, o);
        float mn = fmaxf(m, partial);
        float f = __expf(m - mn);
        float pp = __expf(partial - mn);
        s = s * f + pp;
#pragma unroll
        for (int t = 0; t < 16; ++t) acc[t] = acc[t] * f + pp * xf[t];
        m = mn;
    }

    const float dinv = 1.f / (s + 1e-16f);
    float* op = p.x2c + (long)w * HID + c0;
#pragma unroll
    for (int t = 0; t < 4; ++t) {
        float4 b4 = *(const float4*)&p.g2bias[c0 + t * 4];
        float4 wv = {acc[t*4] * dinv + b4.x, acc[t*4+1] * dinv + b4.y,
                     acc[t*4+2] * dinv + b4.z, acc[t*4+3] * dinv + b4.w};
        *(float4*)&op[t * 4] = wv;
    }
}

__device__ void dev_attn(const float* part, const float* bias, bf16* out,
                         int L, int R, int job, LdsU& u)
{
    const int b = job >> 2, h = job & 3;
    const int tid = threadIdx.x;
    const size_t PS = (size_t)R * 3 * HID;
    for (int i = tid; i < L * 256; i += 256) {
        const int l = i >> 8, d = i & 255;
        const long rb = (long)(b * L + l) * 3 * HID + h * 256 + d;
        float sq = part[rb], sk = part[rb + HID], sv = part[rb + 2 * HID];
#pragma unroll
        for (int k = 1; k < 4; ++k) {
            sq += part[k * PS + rb];
            sk += part[k * PS + rb + HID];
            sv += part[k * PS + rb + 2 * HID];
        }
        u.a.q[l][d] = sq + bias[h * 256 + d];
        u.a.k[l][d] = sk + bias[HID + h * 256 + d];
        u.a.v[l][d] = sv + bias[2 * HID + h * 256 + d];
    }
    __syncthreads();
    if (tid < L * L) {
        const int l1 = tid / L, l2 = tid - l1 * L;
        float s = 0.f;
        for (int d = 0; d < 256; ++d) s += u.a.q[l1][d] * u.a.k[l2][d];
        u.a.sc[l1][l2] = s * 0.0625f;
    }
    __syncthreads();
    if (tid < L) {
        float mx = -1e30f;
        for (int j = 0; j < L; ++j) mx = fmaxf(mx, u.a.sc[tid][j]);
        float ssum = 0.f;
        for (int j = 0; j < L; ++j) { float e = expf(u.a.sc[tid][j] - mx); u.a.sc[tid][j] = e; ssum += e; }
        const float inv = 1.f / ssum;
        for (int j = 0; j < L; ++j) u.a.sc[tid][j] *= inv;
    }
    __syncthreads();
    for (int l1 = 0; l1 < L; ++l1) {
        float a = 0.f;
        for (int l2 = 0; l2 < L; ++l2) a += u.a.sc[l1][l2] * u.a.v[l2][tid];
        out[(long)(b * L + l1) * HID + h * 256 + tid] = (bf16)a;
    }
    __syncthreads();
}

__device__ void dev_cls(const MP& p, int job)
{
    const int row = job * 4 + (threadIdx.x >> 6);
    const int lane = threadIdx.x & 63;
    if (row >= p.R) return;
    float s = 0.f;
    for (int c = lane; c < HID; c += 64) s += p.srcbuf[(long)row * HID + c] * p.cls_w[c];
    for (int o = 32; o; o >>= 1) s += __shfl_down(s, o);
    if (lane == 0) p.outp[row] = s + p.cls_b[0];
}

// ---------------------------------------------------------------------------
// the megakernel
// ---------------------------------------------------------------------------
__global__ __launch_bounds__(256) void mega_kernel(MP p, CvtTArgs ta, int nT,
                                                   CvtArgs ca, int nC)
{
    __shared__ LdsU u;
    const int NB = gridDim.x;
    int ep = 0;

    const int gE   = (p.E + 255) >> 8;
    const int gMn2 = (p.Nn + 127) >> 7;
    const int gMn1 = p.cap1 >> 7;
    const long MNr = (long)p.R * HID;

    // S1: all weight converts/transposes + pass0
    {
        const int n1 = nT + nC + gE;
        for (int job = blockIdx.x; job < n1; job += NB) {
            if (job < nT) dev_cvt_t(ta, job, u);
            else if (job < nT + nC) dev_cvt(ca, job - nT);
            else dev_pass0(p, job - nT - nC);
        }
    }
    gsync(p.bar, ++ep * NB);
    // S2: compact1
    for (int job = blockIdx.x; job < (p.Nn + 255) >> 8; job += NB)
        dev_compact(p.f1, p.map1, p.list1, p.cnt1, p.Nn, job);
    gsync(p.bar, ++ep * NB);
    // S3: pass1
    for (int job = blockIdx.x; job < gE; job += NB) dev_pass1(p, job);
    gsync(p.bar, ++ep * NB);
    // S4: compact2
    for (int job = blockIdx.x; job < (p.Nn + 255) >> 8; job += NB)
        dev_compact(p.f2, p.map2, p.list2, p.cnt2, p.Nn, job);
    gsync(p.bar, ++ep * NB);
    // S5: gathers + cross-attn V projection
    {
        int c2 = *p.cnt2, c1 = *p.cnt1;
        for (int job = blockIdx.x; job < 8 + 2048 + 512; job += NB) {
            if (job < 8)
                dev_gemm(p.imgb, p.xa_v_b, p.xa_in_b + 2 * HID, p.vprojb,
                         p.B, HID, HID, nullptr, 0, 1, job, 0, u);
            else if (job < 8 + 2048)
                dev_gather(p.nf, p.nf2c, p.list2, c2, job - 8, 2048, p.DF);
            else
                dev_gather(p.nf, p.nf1c, p.list1, c1, job - 8 - 2048, 512, p.DF);
        }
    }
    gsync(p.bar, ++ep * NB);
    // S6: GAT1 l/r projections + cross-attn O projection
    {
        const int jl = 8 * gMn2, jr = 8 * gMn1;
        for (int job = blockIdx.x; job < jl + jr + 8; job += NB) {
            if (job < jl)
                dev_gemm(p.nf2c, p.w1lT, p.g1bl, p.xlc, p.Nn, HID, p.DF,
                         p.cnt2, 0, 1, job % 8, job / 8, u);
            else if (job < jl + jr) {
                int q = job - jl;
                dev_gemm(p.nf1c, p.w1rT, p.g1br, p.xrc, p.cap1, HID, p.DF,
                         p.cnt1, 0, 1, q % 8, q / 8, u);
            } else
                dev_gemm(p.vprojb, p.xa_o_b, p.xa_out_b, p.attnb,
                         p.B, HID, HID, nullptr, 0, 0, job - jl - jr, 0, u);
        }
    }
    gsync(p.bar, ++ep * NB);
    // S7: GAT1 aggregation
    {
        int c1 = *p.cnt1;
        for (int job = blockIdx.x; job < (p.cap1 >> 2); job += NB)
            dev_wave1(p, job, c1);
    }
    gsync(p.bar, ++ep * NB);
    // S8: GAT2 stacked [l|r] projection
    for (int job = blockIdx.x; job < 16 * gMn1; job += NB)
        dev_gemm(p.x1c, p.w2T, p.bias2, p.x12c, p.cap1, 2 * HID, HID,
                 p.cnt1, 0, 1, job % 16, job / 16, u);
    gsync(p.bar, ++ep * NB);
    // S9: GAT2 aggregation (targets)
    for (int job = blockIdx.x; job < (p.L + 3) >> 2; job += NB) dev_wave2(p, job);
    gsync(p.bar, ++ep * NB);
    // S10: cross LN
    for (int job = blockIdx.x; job < p.R; job += NB) dev_ln_cross(p, job, u.red);
    gsync(p.bar, ++ep * NB);

    // xl FF block
    for (int job = blockIdx.x; job < 16 * 4 * 4; job += NB) {
        int bn = job % 16, rem = job / 16;
        dev_bsk(p.srcb16, p.xl1w, p.skpart, p.R, FFD, HID, 4, bn, rem % 4, rem / 4, u);
    }
    gsync(p.bar, ++ep * NB);
    for (int job = blockIdx.x; job < (int)(((long)p.R * FFD) >> 10); job += NB)
        dev_red16(p.skpart, p.xl_l1_b, p.h1b, (long)p.R * FFD, FFD, 4, job);
    gsync(p.bar, ++ep * NB);
    for (int job = blockIdx.x; job < 8 * 4 * 8; job += NB) {
        int bn = job % 8, rem = job / 8;
        dev_bsk(p.h1b, p.xl2w, p.skpart, p.R, HID, FFD, 8, bn, rem % 4, rem / 4, u);
    }
    gsync(p.bar, ++ep * NB);
    for (int job = blockIdx.x; job < p.R; job += NB)
        dev_red_ln(p.skpart, p.xl_l2_b, p.srcbuf, p.srcb16,
                   p.xl_n2_g, p.xl_n2_b, MNr, 8, job, u.red);
    gsync(p.bar, ++ep * NB);

    // 2 encoder layers
    for (int enc = 0; enc < 2; ++enc) {
        const bf16* einw = p.einw[enc];
        const bf16* eoutw = p.eoutw[enc];
        const bf16* el1w = p.el1w[enc];
        const bf16* el2w = p.el2w[enc];
        const float* binq = p.enc_in_b + (size_t)enc * 3 * HID;
        const float* bout = p.enc_out_b + (size_t)enc * HID;
        const float* bl1  = p.enc_l1_b + (size_t)enc * FFD;
        const float* bl2  = p.enc_l2_b + (size_t)enc * HID;

        for (int job = blockIdx.x; job < 24 * 4 * 4; job += NB) {
            int bn = job % 24, rem = job / 24;
            dev_bsk(p.srcb16, einw, p.skpart, p.R, 3 * HID, HID, 4, bn, rem % 4, rem / 4, u);
        }
        gsync(p.bar, ++ep * NB);
        for (int job = blockIdx.x; job < p.B * 4; job += NB)
            dev_attn(p.skpart, binq, p.ffb16, p.L, p.R, job, u);
        gsync(p.bar, ++ep * NB);
        for (int job = blockIdx.x; job < 8 * 4 * 4; job += NB) {
            int bn = job % 8, rem = job / 8;
            dev_bsk(p.ffb16, eoutw, p.skpart, p.R, HID, HID, 4, bn, rem % 4, rem / 4, u);
        }
        gsync(p.bar, ++ep * NB);
        for (int job = blockIdx.x; job < p.R; job += NB)
            dev_red_ln(p.skpart, bout, p.srcbuf, p.srcb16,
                       p.enc_n1_g + (size_t)enc * HID, p.enc_n1_b + (size_t)enc * HID,
                       MNr, 4, job, u.red);
        gsync(p.bar, ++ep * NB);
        for (int job = blockIdx.x; job < 16 * 4 * 4; job += NB) {
            int bn = job % 16, rem = job / 16;
            dev_bsk(p.srcb16, el1w, p.skpart, p.R, FFD, HID, 4, bn, rem % 4, rem / 4, u);
        }
        gsync(p.bar, ++ep * NB);
        for (int job = blockIdx.x; job < (int)(((long)p.R * FFD) >> 10); job += NB)
            dev_red16(p.skpart, bl1, p.h1b, (long)p.R * FFD, FFD, 4, job);
        gsync(p.bar, ++ep * NB);
        for (int job = blockIdx.x; job < 8 * 4 * 8; job += NB) {
            int bn = job % 8, rem = job / 8;
            dev_bsk(p.h1b, el2w, p.skpart, p.R, HID, FFD, 8, bn, rem % 4, rem / 4, u);
        }
        gsync(p.bar, ++ep * NB);
        for (int job = blockIdx.x; job < p.R; job += NB)
            dev_red_ln(p.skpart, bl2, p.srcbuf, p.srcb16,
                       p.enc_n2_g + (size_t)enc * HID, p.enc_n2_b + (size_t)enc * HID,
                       MNr, 8, job, u.red);
        gsync(p.bar, ++ep * NB);
    }

    // classifier
    for (int job = blockIdx.x; job < (p.R + 3) >> 2; job += NB) dev_cls(p, job);
}

// ---------------------------------------------------------------------------
// zero flags/counters/barrier + build concat bias for GAT2
// ---------------------------------------------------------------------------
__global__ void zero_prep_kernel(int* __restrict__ zp, int Z,
                                 const float* __restrict__ bl,
                                 const float* __restrict__ br,
                                 float* __restrict__ bias2)
{
    int i = blockIdx.x * 256 + threadIdx.x;
    if (i < Z) zp[i] = 0;
    int j = i - Z;
    if (j >= 0 && j < HID) bias2[j] = bl[j];
    else if (j >= HID && j < 2 * HID) bias2[j] = br[j - HID];
}

// ---------------------------------------------------------------------------
extern "C" void kernel_launch(void* const* d_in, const int* in_sizes, int n_in,
                              void* d_out, int out_size, void* d_ws, size_t ws_size,
                              hipStream_t stream)
{
    const float* img_feat      = (const float*)d_in[0];
    const float* node_features = (const float*)d_in[1];
    const int*   edge_index    = (const int*)d_in[2];
    const int*   target_idx    = (const int*)d_in[3];
    const float* gat1_wl  = (const float*)d_in[4];
    const float* gat1_bl  = (const float*)d_in[5];
    const float* gat1_wr  = (const float*)d_in[6];
    const float* gat1_br  = (const float*)d_in[7];
    const float* gat1_att = (const float*)d_in[8];
    const float* gat1_bias= (const float*)d_in[9];
    const float* gat2_wl  = (const float*)d_in[10];
    const float* gat2_bl  = (const float*)d_in[11];
    const float* gat2_wr  = (const float*)d_in[12];
    const float* gat2_br  = (const float*)d_in[13];
    const float* gat2_att = (const float*)d_in[14];
    const float* gat2_bias= (const float*)d_in[15];
    const float* xa_in_w  = (const float*)d_in[16];
    const float* xa_in_b  = (const float*)d_in[17];
    const float* xa_out_w = (const float*)d_in[18];
    const float* xa_out_b = (const float*)d_in[19];
    const float* xl_l1_w  = (const float*)d_in[20];
    const float* xl_l1_b  = (const float*)d_in[21];
    const float* xl_l2_w  = (const float*)d_in[22];
    const float* xl_l2_b  = (const float*)d_in[23];
    const float* xl_n1_g  = (const float*)d_in[24];
    const float* xl_n1_b  = (const float*)d_in[25];
    const float* xl_n2_g  = (const float*)d_in[26];
    const float* xl_n2_b  = (const float*)d_in[27];
    const float* enc_in_w = (const float*)d_in[28];
    const float* enc_in_b = (const float*)d_in[29];
    const float* enc_out_w= (const float*)d_in[30];
    const float* enc_out_b= (const float*)d_in[31];
    const float* enc_l1_w = (const float*)d_in[32];
    const float* enc_l1_b = (const float*)d_in[33];
    const float* enc_l2_w = (const float*)d_in[34];
    const float* enc_l2_b = (const float*)d_in[35];
    const float* enc_n1_g = (const float*)d_in[36];
    const float* enc_n1_b = (const float*)d_in[37];
    const float* enc_n2_g = (const float*)d_in[38];
    const float* enc_n2_b = (const float*)d_in[39];
    const float* cls_w    = (const float*)d_in[40];
    const float* cls_b    = (const float*)d_in[41];

    const int DF = in_sizes[4] / HID;          // 768
    const int Nn = in_sizes[1] / DF;           // 8000
    const int E  = in_sizes[2] / 2;            // 104000
    const int L  = in_sizes[3];                // 14 (<= 16)
    const int B  = in_sizes[0] / HID;          // 32
    const int R  = B * L;                      // 448

    const int cap1 = ((L * 129 + 127) / 128) * 128;

    char* basep = (char*)d_ws;
    size_t off = 0;
    auto alloc = [&](size_t bytes) -> char* {
        char* r = basep + off; off += (bytes + 255) & ~(size_t)255; return r;
    };

    MP p;
    p.nf = node_features; p.ei = edge_index; p.tgt = target_idx;
    p.g1bl = gat1_bl; p.g1br = gat1_br; p.g1att = gat1_att; p.g1bias = gat1_bias;
    p.g2att = gat2_att; p.g2bias = gat2_bias;
    p.xa_in_b = xa_in_b; p.xa_out_b = xa_out_b;
    p.xl_l1_b = xl_l1_b; p.xl_l2_b = xl_l2_b;
    p.xl_n1_g = xl_n1_g; p.xl_n1_b = xl_n1_b; p.xl_n2_g = xl_n2_g; p.xl_n2_b = xl_n2_b;
    p.enc_in_b = enc_in_b; p.enc_out_b = enc_out_b; p.enc_l1_b = enc_l1_b; p.enc_l2_b = enc_l2_b;
    p.enc_n1_g = enc_n1_g; p.enc_n1_b = enc_n1_b; p.enc_n2_g = enc_n2_g; p.enc_n2_b = enc_n2_b;
    p.cls_w = cls_w; p.cls_b = cls_b;
    p.DF = DF; p.Nn = Nn; p.E = E; p.L = L; p.B = B; p.R = R; p.cap1 = cap1;
    p.outp = (float*)d_out;

    p.w1lT = (bf16*)alloc((size_t)DF * HID * 2);
    p.w1rT = (bf16*)alloc((size_t)DF * HID * 2);
    p.w2T  = (bf16*)alloc((size_t)2 * HID * HID * 2);
    p.bias2 = (float*)alloc((size_t)2 * HID * 4);

    p.xa_v_b = (bf16*)alloc((size_t)HID * HID * 2);
    p.xa_o_b = (bf16*)alloc((size_t)HID * HID * 2);
    p.xl1w   = (bf16*)alloc((size_t)FFD * HID * 2);
    p.xl2w   = (bf16*)alloc((size_t)HID * FFD * 2);
    for (int i = 0; i < 2; ++i) {
        p.einw[i]  = (bf16*)alloc((size_t)3 * HID * HID * 2);
        p.eoutw[i] = (bf16*)alloc((size_t)HID * HID * 2);
        p.el1w[i]  = (bf16*)alloc((size_t)FFD * HID * 2);
        p.el2w[i]  = (bf16*)alloc((size_t)HID * FFD * 2);
    }
    p.imgb = (bf16*)alloc((size_t)B * HID * 2);

    int* zbase = (int*)alloc((size_t)(2 * Nn + cap1 + 32) * 4);
    p.f1 = zbase;
    p.f2 = p.f1 + Nn;
    p.cntE1 = p.f2 + Nn;
    p.cntE0 = p.cntE1 + cap1;
    p.cnt1 = p.cntE0 + 16;
    p.cnt2 = p.cnt1 + 1;
    p.bar  = p.cnt2 + 1;
    const int Z = 2 * Nn + cap1 + 20;

    p.map1  = (int*)alloc((size_t)Nn * 4);
    p.map2  = (int*)alloc((size_t)Nn * 4);
    p.list1 = (int*)alloc((size_t)cap1 * 4);
    p.list2 = (int*)alloc((size_t)Nn * 4);
    p.srcs0 = (int*)alloc((size_t)16 * 128 * 4);
    p.srcs1 = (int*)alloc((size_t)cap1 * 128 * 4);

    p.nf2c = (bf16*)alloc((size_t)Nn * DF * 2);
    p.nf1c = (bf16*)alloc((size_t)cap1 * DF * 2);
    p.xlc  = (bf16*)alloc((size_t)Nn * HID * 2);
    p.xrc  = (bf16*)alloc((size_t)cap1 * HID * 2);
    p.x1c  = (bf16*)alloc((size_t)cap1 * HID * 2);
    p.x12c = (bf16*)alloc((size_t)cap1 * 2 * HID * 2);
    p.x2c  = (float*)alloc((size_t)16 * HID * 4);
    p.vprojb = (bf16*)alloc((size_t)B * HID * 2);
    p.attnb  = (float*)alloc((size_t)B * HID * 4);
    p.srcbuf = (float*)alloc((size_t)R * HID * 4);
    p.srcb16 = (bf16*)alloc((size_t)R * HID * 2);
    p.h1b    = (bf16*)alloc((size_t)R * FFD * 2);
    p.ffb16  = (bf16*)alloc((size_t)R * HID * 2);
    p.skpart = (float*)alloc((size_t)4 * R * 3 * HID * 4);

    // cvt-transpose job table (GAT weights)
    CvtTArgs ta; ta.n = 4;
    int nT = 0;
    ta.e[0] = {gat1_wl, p.w1lT, DF, HID, nT};  nT += (HID / 32) * (DF / 32);
    ta.e[1] = {gat1_wr, p.w1rT, DF, HID, nT};  nT += (HID / 32) * (DF / 32);
    ta.e[2] = {gat2_wl, p.w2T, HID, HID, nT};  nT += (HID / 32) * (HID / 32);
    ta.e[3] = {gat2_wr, p.w2T + (size_t)HID * HID, HID, HID, nT};
    nT += (HID / 32) * (HID / 32);

    // linear cvt job table (transformer weights + img)
    CvtArgs ca; int nC = 0, kk = 0;
    auto add = [&](const float* s, bf16* d, long elems) {
        ca.e[kk++] = {s, d, nC}; nC += (int)(elems / 1024);
    };
    add(img_feat, p.imgb, (long)B * HID);
    add(xa_in_w + (size_t)2 * HID * HID, p.xa_v_b, (long)HID * HID);
    add(xa_out_w, p.xa_o_b, (long)HID * HID);
    add(xl_l1_w, p.xl1w, (long)FFD * HID);
    add(xl_l2_w, p.xl2w, (long)HID * FFD);
    for (int i = 0; i < 2; ++i) {
        add(enc_in_w  + (size_t)i * 3 * HID * HID, p.einw[i],  (long)3 * HID * HID);
        add(enc_out_w + (size_t)i * HID * HID,     p.eoutw[i], (long)HID * HID);
        add(enc_l1_w  + (size_t)i * FFD * HID,     p.el1w[i],  (long)FFD * HID);
        add(enc_l2_w  + (size_t)i * HID * FFD,     p.el2w[i],  (long)HID * FFD);
    }
    ca.n = kk;

    zero_prep_kernel<<<(Z + 2 * HID + 255) / 256, 256, 0, stream>>>(
        zbase, Z, gat2_bl, gat2_br, p.bias2);

    // occupancy-derived grid (cached; host-only queries, graph-capture safe)
    static int coopGrid = -1;
    if (coopGrid < 0) {
        int mb = 0;
        (void)hipOccupancyMaxActiveBlocksPerMultiprocessor(&mb, mega_kernel, 256, 0);
        if (mb < 1) mb = 1;
        int cus = 256;
        hipDeviceProp_t prop;
        int dev = 0;
        if (hipGetDevice(&dev) == hipSuccess &&
            hipGetDeviceProperties(&prop, dev) == hipSuccess &&
            prop.multiProcessorCount > 0)
            cus = prop.multiProcessorCount;
        long g = (long)mb * cus;
        coopGrid = (int)(g < GRID_CAP ? g : GRID_CAP);
        if (coopGrid < 1) coopGrid = 1;
    }

    void* args[] = {(void*)&p, (void*)&ta, (void*)&nT, (void*)&ca, (void*)&nC};
    hipError_t err = hipLaunchCooperativeKernel((const void*)mega_kernel,
                                                dim3(coopGrid), dim3(256),
                                                args, 0, stream);
    if (err != hipSuccess) {
        // fallback: normal launch at <= co-resident capacity (atomic barrier
        // remains valid because grid fits on the device simultaneously)
        mega_kernel<<<coopGrid, 256, 0, stream>>>(p, ta, nT, ca, nC);
    }
}